// Round 9
// baseline (1077.622 us; speedup 1.0000x reference)
//
#include <hip/hip_runtime.h>
#include <hip/hip_bf16.h>

#define EPSV 1e-8f

typedef short bf16x8 __attribute__((ext_vector_type(8)));
typedef float f32x4  __attribute__((ext_vector_type(4)));

__device__ __forceinline__ float silu_f(float x) {
    return x * __builtin_amdgcn_rcpf(1.0f + __expf(-x));
}
__device__ __forceinline__ float bf2f(short v) {
    return __uint_as_float(((unsigned int)(unsigned short)v) << 16);
}
__device__ __forceinline__ short f2bfs(float f) {
    __hip_bfloat16 h = __float2bfloat16(f);
    return *(short*)&h;
}

// ======================= weight repack: f32 KxN(row-major, N=128) -> bf16 MFMA-B frags
#define MAXM 24
struct PackArgs {
    const float* src[MAXM];
    unsigned int doff[MAXM];
    int nchunk[MAXM];
    int nmat;
};

__global__ __launch_bounds__(256) void repack_kernel(PackArgs pa, __hip_bfloat16* base)
{
    int bid = blockIdx.x;
    int m = 0, c = bid;
    while (m < pa.nmat && c >= pa.nchunk[m]) { c -= pa.nchunk[m]; ++m; }
    const float* src = pa.src[m];
    __hip_bfloat16* dst = base + pa.doff[m] + (size_t)c * 4096;
    for (int o = threadIdx.x; o < 4096; o += 256) {
        int j = o & 7, n = (o >> 3) & 127, g = o >> 10;
        dst[o] = __float2bfloat16(src[(size_t)(c * 32 + g * 8 + j) * 128 + n]);
    }
}

// ======================= edge dst-sort: histogram -> scan -> scatter
__global__ __launch_bounds__(256) void hist_kernel(
    const int* __restrict__ ei, int* __restrict__ cnt, int E, int N)
{
    int e = blockIdx.x * 256 + threadIdx.x;
    int Etot = E + N;
    if (e < Etot) {
        int d = (e < E) ? ei[E + e] : (e - E);
        atomicAdd(&cnt[d], 1);
    }
}

__global__ __launch_bounds__(256) void scan_block_kernel(
    const int* __restrict__ cnt, int* __restrict__ off, int* __restrict__ part, int n)
{
    __shared__ int sdata[256];
    const int tid = threadIdx.x;
    const int base = blockIdx.x * 4096 + tid * 16;
    int loc[16]; int s = 0;
    #pragma unroll
    for (int i = 0; i < 16; ++i) {
        int idx = base + i;
        int v = (idx < n) ? cnt[idx] : 0;
        loc[i] = s; s += v;
    }
    sdata[tid] = s;
    __syncthreads();
    for (int st = 1; st < 256; st <<= 1) {
        int v = (tid >= st) ? sdata[tid - st] : 0;
        __syncthreads();
        sdata[tid] += v;
        __syncthreads();
    }
    int texc = (tid > 0) ? sdata[tid - 1] : 0;
    #pragma unroll
    for (int i = 0; i < 16; ++i) {
        int idx = base + i;
        if (idx < n) off[idx] = texc + loc[i];
    }
    if (tid == 255) part[blockIdx.x] = sdata[255];
}

__global__ void scan_part_kernel(int* part, int np)
{
    if (threadIdx.x == 0 && blockIdx.x == 0) {
        int run = 0;
        for (int i = 0; i < np; ++i) { int v = part[i]; part[i] = run; run += v; }
    }
}

__global__ __launch_bounds__(256) void scan_add_kernel(
    int* __restrict__ off, const int* __restrict__ part, int n)
{
    int idx = blockIdx.x * 4096 + threadIdx.x * 16;
    int p = part[blockIdx.x];
    #pragma unroll
    for (int i = 0; i < 16; ++i)
        if (idx + i < n) off[idx + i] += p;
}

__global__ __launch_bounds__(256) void scatter_kernel(
    const int* __restrict__ ei, int* __restrict__ off,
    int* __restrict__ esrc, int* __restrict__ edst, int E, int N)
{
    int e = blockIdx.x * 256 + threadIdx.x;
    int Etot = E + N;
    if (e < Etot) {
        int s, d;
        if (e < E) { s = ei[e]; d = ei[E + e]; }
        else       { s = d = e - E; }
        int p = atomicAdd(&off[d], 1);
        esrc[p] = s; edst[p] = d;
    }
}

// ======================= core MFMA tile GEMM (A in LDS, B packed global; 4 waves x 32 cols)
template<int LDA>
__device__ __forceinline__ void mfma_gemm(const __hip_bfloat16 (*At)[LDA], int acol0,
                                          const __hip_bfloat16* __restrict__ Bp,
                                          int kchunks, int w, int lane, f32x4 acc[4][2])
{
    const int ar = lane & 15, g = lane >> 4;
    const int bc = w * 32 + (lane & 15);
    for (int c = 0; c < kchunks; ++c) {
        const int ao = acol0 + c * 32 + g * 8;
        bf16x8 a0 = *(const bf16x8*)&At[ar +  0][ao];
        bf16x8 a1 = *(const bf16x8*)&At[ar + 16][ao];
        bf16x8 a2 = *(const bf16x8*)&At[ar + 32][ao];
        bf16x8 a3 = *(const bf16x8*)&At[ar + 48][ao];
        const __hip_bfloat16* bb = Bp + ((size_t)((c * 4 + g) * 128) + bc) * 8;
        bf16x8 b0 = *(const bf16x8*)(bb);
        bf16x8 b1 = *(const bf16x8*)(bb + 128);
        acc[0][0] = __builtin_amdgcn_mfma_f32_16x16x32_bf16(a0, b0, acc[0][0], 0, 0, 0);
        acc[1][0] = __builtin_amdgcn_mfma_f32_16x16x32_bf16(a1, b0, acc[1][0], 0, 0, 0);
        acc[2][0] = __builtin_amdgcn_mfma_f32_16x16x32_bf16(a2, b0, acc[2][0], 0, 0, 0);
        acc[3][0] = __builtin_amdgcn_mfma_f32_16x16x32_bf16(a3, b0, acc[3][0], 0, 0, 0);
        acc[0][1] = __builtin_amdgcn_mfma_f32_16x16x32_bf16(a0, b1, acc[0][1], 0, 0, 0);
        acc[1][1] = __builtin_amdgcn_mfma_f32_16x16x32_bf16(a1, b1, acc[1][1], 0, 0, 0);
        acc[2][1] = __builtin_amdgcn_mfma_f32_16x16x32_bf16(a2, b1, acc[2][1], 0, 0, 0);
        acc[3][1] = __builtin_amdgcn_mfma_f32_16x16x32_bf16(a3, b1, acc[3][1], 0, 0, 0);
    }
}

__device__ __forceinline__ void zacc(f32x4 acc[4][2]) {
    #pragma unroll
    for (int r = 0; r < 4; ++r)
        #pragma unroll
        for (int c = 0; c < 2; ++c) acc[r][c] = (f32x4){0.f, 0.f, 0.f, 0.f};
}

// ======================= fused embed + layer-0 precompute (all MFMA):
// h = bf16(hin) @ embW + embb ; U0 = h@W1a+b1 ; V0 = h@W1b ; wnum0 = silu(h@cW1+cb1).cW2+cb2
__global__ __launch_bounds__(256) void embed_pre_kernel(
    const float* __restrict__ hin,
    const __hip_bfloat16* __restrict__ embWp, const float* __restrict__ embb,
    const __hip_bfloat16* __restrict__ W1p, const float* __restrict__ b1,
    const __hip_bfloat16* __restrict__ cW1p,
    const float* __restrict__ cb1, const float* __restrict__ cW2,
    const float* __restrict__ cb2,
    float* __restrict__ hbuf, __hip_bfloat16* __restrict__ h16,
    __hip_bfloat16* __restrict__ U16, __hip_bfloat16* __restrict__ V16,
    float* __restrict__ wnum, int N)
{
    __shared__ __hip_bfloat16 a_e[64][72];
    __shared__ __hip_bfloat16 a_h[64][136];
    __shared__ float redw[64][4];
    const int t = threadIdx.x;
    const int nb = blockIdx.x * 64;
    const int lane = t & 63, w = t >> 6, g = lane >> 4, l15 = lane & 15;

    // stage hin (f32 -> bf16), 64 rows x 8 octets
    #pragma unroll
    for (int it = 0; it < 2; ++it) {
        int flat = t + 256 * it;
        int c8 = flat & 7, e = flat >> 3;
        int node = nb + e; if (node >= N) node = N - 1;
        const float* hp = hin + (size_t)node * 64 + c8 * 8;
        float4 v0 = *(const float4*)hp, v1 = *(const float4*)(hp + 4);
        bf16x8 r;
        r[0] = f2bfs(v0.x); r[1] = f2bfs(v0.y); r[2] = f2bfs(v0.z); r[3] = f2bfs(v0.w);
        r[4] = f2bfs(v1.x); r[5] = f2bfs(v1.y); r[6] = f2bfs(v1.z); r[7] = f2bfs(v1.w);
        *(bf16x8*)(&a_e[e][c8 * 8]) = r;
    }
    __syncthreads();

    const int colA = w * 32 + l15, colB = colA + 16;
    f32x4 acc[4][2];

    // embed GEMM (K=64)
    zacc(acc);
    mfma_gemm<72>(a_e, 0, embWp, 2, w, lane, acc);
    {
        float bA = embb[colA], bB = embb[colB];
        #pragma unroll
        for (int r = 0; r < 4; ++r)
            #pragma unroll
            for (int q = 0; q < 4; ++q) {
                int row = r * 16 + g * 4 + q;
                int node = nb + row;
                float va = acc[r][0][q] + bA, vb = acc[r][1][q] + bB;
                __hip_bfloat16 ha = __float2bfloat16(va), hb = __float2bfloat16(vb);
                a_h[row][colA] = ha; a_h[row][colB] = hb;
                if (node < N) {
                    size_t off = (size_t)node * 128;
                    hbuf[off + colA] = va; hbuf[off + colB] = vb;
                    h16[off + colA] = ha; h16[off + colB] = hb;
                }
            }
    }
    __syncthreads();

    // U0 (+b1)
    zacc(acc);
    mfma_gemm<136>(a_h, 0, W1p, 4, w, lane, acc);
    {
        float bA = b1[colA], bB = b1[colB];
        #pragma unroll
        for (int r = 0; r < 4; ++r)
            #pragma unroll
            for (int q = 0; q < 4; ++q) {
                int node = nb + r * 16 + g * 4 + q;
                if (node < N) {
                    U16[(size_t)node * 128 + colA] = __float2bfloat16(acc[r][0][q] + bA);
                    U16[(size_t)node * 128 + colB] = __float2bfloat16(acc[r][1][q] + bB);
                }
            }
    }
    // V0
    zacc(acc);
    mfma_gemm<136>(a_h, 0, W1p + 4 * 4096, 4, w, lane, acc);
    #pragma unroll
    for (int r = 0; r < 4; ++r)
        #pragma unroll
        for (int q = 0; q < 4; ++q) {
            int node = nb + r * 16 + g * 4 + q;
            if (node < N) {
                V16[(size_t)node * 128 + colA] = __float2bfloat16(acc[r][0][q]);
                V16[(size_t)node * 128 + colB] = __float2bfloat16(acc[r][1][q]);
            }
        }
    // wnum0
    zacc(acc);
    mfma_gemm<136>(a_h, 0, cW1p, 4, w, lane, acc);
    {
        float cb1A = cb1[colA], cb1B = cb1[colB];
        float wA = cW2[colA], wB = cW2[colB];
        #pragma unroll
        for (int r = 0; r < 4; ++r)
            #pragma unroll
            for (int q = 0; q < 4; ++q) {
                float p = silu_f(acc[r][0][q] + cb1A) * wA
                        + silu_f(acc[r][1][q] + cb1B) * wB;
                p += __shfl_xor(p, 1);
                p += __shfl_xor(p, 2);
                p += __shfl_xor(p, 4);
                p += __shfl_xor(p, 8);
                if (l15 == 0) redw[r * 16 + g * 4 + q][w] = p;
            }
    }
    __syncthreads();
    if (t < 64 && nb + t < N)
        wnum[nb + t] = redw[t][0] + redw[t][1] + redw[t][2] + redw[t][3] + cb2[0];
}

// ======================= per-layer edge kernel (64 edges / 256 threads)
__global__ __launch_bounds__(256) void edge_kernel(
    const __hip_bfloat16* __restrict__ U16, const __hip_bfloat16* __restrict__ V16,
    const float* __restrict__ wnum, const float* __restrict__ posb,
    const int* __restrict__ esrc, const int* __restrict__ edst,
    const float* __restrict__ W1tail,
    const __hip_bfloat16* __restrict__ W2p, const float* __restrict__ b2,
    float* __restrict__ agg, float* __restrict__ pdel, int Etot)
{
    __shared__ __hip_bfloat16 m1s[64][136];    // reused for m2 after GEMM2
    __shared__ int   srcl[64], dstl[64];
    __shared__ float relt[3][64], distl[64], wscl[64];

    const int t = threadIdx.x;
    const int eb = blockIdx.x * 64;
    const int lane = t & 63, w = t >> 6, g = lane >> 4, l15 = lane & 15;

    if (t < 64) {
        int e = eb + t;
        int s = 0, d = -1;
        if (e < Etot) { s = esrc[e]; d = edst[e]; }
        srcl[t] = s; dstl[t] = d;
        int dd = (d < 0) ? 0 : d;
        float rx = posb[3 * s + 0] - posb[3 * dd + 0];
        float ry = posb[3 * s + 1] - posb[3 * dd + 1];
        float rz = posb[3 * s + 2] - posb[3 * dd + 2];
        float dist = sqrtf(rx * rx + ry * ry + rz * rz);
        relt[0][t] = rx; relt[1][t] = ry; relt[2][t] = rz;
        distl[t] = dist;
        wscl[t] = wnum[s] * __builtin_amdgcn_rcpf(dist + EPSV);
    }
    __syncthreads();

    // pdel scatter early — its latency hides under the U/V gathers below
    if (t < 192) {
        int e = t / 3, comp = t % 3;
        if (dstl[e] >= 0)
            atomicAdd(&pdel[(size_t)dstl[e] * 3 + comp], wscl[e] * relt[comp][e]);
    }

    // m1 = silu(U[dst] (b1 folded) + V[src] + dist*wt)  — wt hoisted (c8 j-invariant)
    {
        const int c8 = t & 15, row0 = t >> 4;
        float wt[8];
        *(float4*)&wt[0] = *(const float4*)(W1tail + c8 * 8);
        *(float4*)&wt[4] = *(const float4*)(W1tail + c8 * 8 + 4);
        #pragma unroll
        for (int j = 0; j < 4; ++j) {
            int row = row0 + 16 * j;
            bf16x8 res;
            if (dstl[row] >= 0) {
                int s = srcl[row], d = dstl[row];
                bf16x8 uv = *(const bf16x8*)(U16 + (size_t)d * 128 + c8 * 8);
                bf16x8 vv = *(const bf16x8*)(V16 + (size_t)s * 128 + c8 * 8);
                float dv = distl[row];
                #pragma unroll
                for (int k = 0; k < 8; ++k) {
                    float x = bf2f(uv[k]) + bf2f(vv[k]) + dv * wt[k];
                    res[k] = f2bfs(silu_f(x));
                }
            } else {
                #pragma unroll
                for (int k = 0; k < 8; ++k) res[k] = 0;
            }
            *(bf16x8*)(&m1s[row][c8 * 8]) = res;
        }
    }
    __syncthreads();

    // GEMM2: m2 = m1 @ W2
    const int colA = w * 32 + l15, colB = colA + 16;
    f32x4 acc[4][2];
    zacc(acc);
    mfma_gemm<136>(m1s, 0, W2p, 4, w, lane, acc);
    __syncthreads();   // all m1s reads done; safe to overwrite with m2

    // write silu(m2 + b2) back into the same LDS (bf16)
    {
        float b2a = b2[colA], b2b = b2[colB];
        #pragma unroll
        for (int r = 0; r < 4; ++r)
            #pragma unroll
            for (int q = 0; q < 4; ++q) {
                int row = r * 16 + g * 4 + q;
                m1s[row][colA] = __float2bfloat16(silu_f(acc[r][0][q] + b2a));
                m1s[row][colB] = __float2bfloat16(silu_f(acc[r][1][q] + b2b));
            }
    }
    __syncthreads();

    // segmented reduction (rows dst-sorted): 2 cols/thread x 16 rows, b32 LDS reads
    {
        int cp = t & 63;            // col pair: cols 2cp, 2cp+1
        int qtr = t >> 6;           // row quarter
        int r0 = qtr * 16;
        float a0 = 0.f, a1 = 0.f;
        int cur = dstl[r0];
        #pragma unroll 4
        for (int r = r0; r < r0 + 16; ++r) {
            int d = dstl[r];
            if (d != cur) {
                if (cur >= 0) {
                    atomicAdd(&agg[(size_t)cur * 128 + 2 * cp], a0);
                    atomicAdd(&agg[(size_t)cur * 128 + 2 * cp + 1], a1);
                }
                a0 = a1 = 0.f; cur = d;
            }
            if (d >= 0) {
                unsigned int v = *(const unsigned int*)&m1s[r][2 * cp];
                a0 += bf2f((short)(v & 0xffffu));
                a1 += bf2f((short)(v >> 16));
            }
        }
        if (cur >= 0) {
            atomicAdd(&agg[(size_t)cur * 128 + 2 * cp], a0);
            atomicAdd(&agg[(size_t)cur * 128 + 2 * cp + 1], a1);
        }
    }
}

// ======================= per-layer node kernel
// mode 1: fused precompute for next layer; mode 2: fused output head
__global__ __launch_bounds__(256) void node_mfma_kernel(
    float* __restrict__ hbuf, __hip_bfloat16* __restrict__ h16,
    const float* __restrict__ agg,
    float* __restrict__ posb, const float* __restrict__ pdel,
    const __hip_bfloat16* __restrict__ W1p, const float* __restrict__ b1,
    const __hip_bfloat16* __restrict__ W2p, const float* __restrict__ b2,
    const __hip_bfloat16* __restrict__ nxtW1p, const float* __restrict__ nxt_b1,
    const __hip_bfloat16* __restrict__ nxt_cW1p, const float* __restrict__ nxt_cb1,
    const float* __restrict__ nxt_cW2, const float* __restrict__ nxt_cb2,
    __hip_bfloat16* __restrict__ U16, __hip_bfloat16* __restrict__ V16,
    float* __restrict__ wnum,
    const __hip_bfloat16* __restrict__ oW1p, const float* __restrict__ ob1,
    const __hip_bfloat16* __restrict__ oW2p, const float* __restrict__ ob2,
    float* __restrict__ outp,
    int N, int mode)
{
    __shared__ __hip_bfloat16 a_t[64][264];   // [h | agg] then [newh | agg]
    __shared__ __hip_bfloat16 us[64][136];
    __shared__ float redw[64][4];
    const int t = threadIdx.x;
    const int nb = blockIdx.x * 64;
    const int lane = t & 63, w = t >> 6, g = lane >> 4, l15 = lane & 15;

    #pragma unroll
    for (int it = 0; it < 4; ++it) {
        int flat = t + 256 * it;
        int c = flat & 15, e = flat >> 4;
        int node = nb + e; if (node >= N) node = N - 1;
        *(int4*)(&a_t[e][c * 8]) = *(const int4*)(h16 + (size_t)node * 128 + c * 8);
    }
    #pragma unroll
    for (int it = 0; it < 8; ++it) {
        int flat = t + 256 * it;
        int c = flat & 31, e = flat >> 5;
        int node = nb + e; if (node >= N) node = N - 1;
        float4 v = *(const float4*)(agg + (size_t)node * 128 + c * 4);
        __hip_bfloat16* p = &a_t[e][128 + c * 4];
        p[0] = __float2bfloat16(v.x); p[1] = __float2bfloat16(v.y);
        p[2] = __float2bfloat16(v.z); p[3] = __float2bfloat16(v.w);
    }
    __syncthreads();

    const int colA = w * 32 + l15, colB = colA + 16;
    f32x4 acc[4][2];

    zacc(acc);
    mfma_gemm<264>(a_t, 0, W1p, 8, w, lane, acc);
    {
        float b1a = b1[colA], b1b = b1[colB];
        #pragma unroll
        for (int r = 0; r < 4; ++r)
            #pragma unroll
            for (int q = 0; q < 4; ++q) {
                int row = r * 16 + g * 4 + q;
                us[row][colA] = __float2bfloat16(silu_f(acc[r][0][q] + b1a));
                us[row][colB] = __float2bfloat16(silu_f(acc[r][1][q] + b1b));
            }
    }
    __syncthreads();

    zacc(acc);
    mfma_gemm<136>(us, 0, W2p, 4, w, lane, acc);
    {
        float b2a = b2[colA], b2b = b2[colB];
        #pragma unroll
        for (int r = 0; r < 4; ++r)
            #pragma unroll
            for (int q = 0; q < 4; ++q) {
                int row = r * 16 + g * 4 + q;
                int node = nb + row;
                if (node < N) {
                    size_t off = (size_t)node * 128;
                    float va = hbuf[off + colA] + acc[r][0][q] + b2a;
                    float vb = hbuf[off + colB] + acc[r][1][q] + b2b;
                    hbuf[off + colA] = va; hbuf[off + colB] = vb;
                    __hip_bfloat16 ha = __float2bfloat16(va), hb = __float2bfloat16(vb);
                    h16[off + colA] = ha; h16[off + colB] = hb;
                    a_t[row][colA] = ha; a_t[row][colB] = hb;
                } else {
                    a_t[row][colA] = __float2bfloat16(0.f);
                    a_t[row][colB] = __float2bfloat16(0.f);
                }
            }
    }
    if (t < 192) {
        int e = t / 3, comp = t % 3;
        int node = nb + e;
        if (node < N) posb[3 * node + comp] += pdel[3 * node + comp];
    }

    if (mode == 0) return;
    __syncthreads();   // newh staged in a_t[.][0..127]; all us reads done

    if (mode == 2) {
        // fused output head: out = silu(newh@oW1+ob1)@oW2 + ob2
        zacc(acc);
        mfma_gemm<264>(a_t, 0, oW1p, 4, w, lane, acc);
        {
            float b1a = ob1[colA], b1b = ob1[colB];
            #pragma unroll
            for (int r = 0; r < 4; ++r)
                #pragma unroll
                for (int q = 0; q < 4; ++q) {
                    int row = r * 16 + g * 4 + q;
                    us[row][colA] = __float2bfloat16(silu_f(acc[r][0][q] + b1a));
                    us[row][colB] = __float2bfloat16(silu_f(acc[r][1][q] + b1b));
                }
        }
        __syncthreads();
        zacc(acc);
        mfma_gemm<136>(us, 0, oW2p, 4, w, lane, acc);
        {
            float b2a = ob2[colA], b2b = ob2[colB];
            #pragma unroll
            for (int r = 0; r < 4; ++r)
                #pragma unroll
                for (int q = 0; q < 4; ++q) {
                    int row = r * 16 + g * 4 + q;
                    int node = nb + row;
                    if (node < N) {
                        outp[(size_t)node * 128 + colA] = acc[r][0][q] + b2a;
                        outp[(size_t)node * 128 + colB] = acc[r][1][q] + b2b;
                    }
                }
        }
        return;
    }

    // mode 1: precompute for next layer
    zacc(acc);
    mfma_gemm<264>(a_t, 0, nxtW1p, 4, w, lane, acc);
    {
        float bA = nxt_b1[colA], bB = nxt_b1[colB];
        #pragma unroll
        for (int r = 0; r < 4; ++r)
            #pragma unroll
            for (int q = 0; q < 4; ++q) {
                int node = nb + r * 16 + g * 4 + q;
                if (node < N) {
                    U16[(size_t)node * 128 + colA] = __float2bfloat16(acc[r][0][q] + bA);
                    U16[(size_t)node * 128 + colB] = __float2bfloat16(acc[r][1][q] + bB);
                }
            }
    }
    zacc(acc);
    mfma_gemm<264>(a_t, 0, nxtW1p + 4 * 4096, 4, w, lane, acc);
    #pragma unroll
    for (int r = 0; r < 4; ++r)
        #pragma unroll
        for (int q = 0; q < 4; ++q) {
            int node = nb + r * 16 + g * 4 + q;
            if (node < N) {
                V16[(size_t)node * 128 + colA] = __float2bfloat16(acc[r][0][q]);
                V16[(size_t)node * 128 + colB] = __float2bfloat16(acc[r][1][q]);
            }
        }
    zacc(acc);
    mfma_gemm<264>(a_t, 0, nxt_cW1p, 4, w, lane, acc);
    {
        float cb1A = nxt_cb1[colA], cb1B = nxt_cb1[colB];
        float wA = nxt_cW2[colA], wB = nxt_cW2[colB];
        #pragma unroll
        for (int r = 0; r < 4; ++r)
            #pragma unroll
            for (int q = 0; q < 4; ++q) {
                float p = silu_f(acc[r][0][q] + cb1A) * wA
                        + silu_f(acc[r][1][q] + cb1B) * wB;
                p += __shfl_xor(p, 1);
                p += __shfl_xor(p, 2);
                p += __shfl_xor(p, 4);
                p += __shfl_xor(p, 8);
                if (l15 == 0) redw[r * 16 + g * 4 + q][w] = p;
            }
    }
    __syncthreads();
    if (t < 64 && nb + t < N)
        wnum[nb + t] = redw[t][0] + redw[t][1] + redw[t][2] + redw[t][3] + nxt_cb2[0];
}

// =======================
extern "C" void kernel_launch(void* const* d_in, const int* in_sizes, int n_in,
                              void* d_out, int out_size, void* d_ws, size_t ws_size,
                              hipStream_t stream)
{
    const float* hin  = (const float*)d_in[0];
    const float* pos  = (const float*)d_in[1];
    const int*   ei   = (const int*)d_in[2];
    const float* embW = (const float*)d_in[3];
    const float* embb = (const float*)d_in[4];
    const float* mW1  = (const float*)d_in[5];
    const float* mb1  = (const float*)d_in[6];
    const float* mW2  = (const float*)d_in[7];
    const float* mb2  = (const float*)d_in[8];
    const float* cW1  = (const float*)d_in[9];
    const float* cb1  = (const float*)d_in[10];
    const float* cW2  = (const float*)d_in[11];
    const float* cb2  = (const float*)d_in[12];
    const float* nW1  = (const float*)d_in[13];
    const float* nb1  = (const float*)d_in[14];
    const float* nW2  = (const float*)d_in[15];
    const float* nb2  = (const float*)d_in[16];
    const float* oW1  = (const float*)d_in[17];
    const float* ob1  = (const float*)d_in[18];
    const float* oW2  = (const float*)d_in[19];
    const float* ob2  = (const float*)d_in[20];

    const int N = in_sizes[0] / 64;
    const int E = in_sizes[2] / 2;
    const int Etot = E + N;

    float* hbuf = (float*)d_ws;                                  // N*128 f32
    float* aggb = hbuf + (size_t)N * 128;                        // N*128 f32
    float* posb = aggb + (size_t)N * 128;                        // N*3
    float* pdel = posb + (size_t)N * 3;                          // N*3
    float* wnum = pdel + (size_t)N * 3;                          // N f32
    __hip_bfloat16* h16 = (__hip_bfloat16*)(wnum + N);           // N*128 bf16
    __hip_bfloat16* U16 = h16 + (size_t)N * 128;                 // N*128 bf16
    __hip_bfloat16* V16 = U16 + (size_t)N * 128;                 // N*128 bf16
    __hip_bfloat16* packed = V16 + (size_t)N * 128;              // 122*4096 bf16
    int* cnt  = (int*)(packed + 122 * 4096);                     // N
    int* soff = cnt + N;                                         // N
    int* part = soff + N;                                        // 64
    int* esrc = part + 64;                                       // Etot
    int* edst = esrc + Etot;                                     // Etot
    float* outp = (float*)d_out;

    PackArgs pa;
    int nm = 0; unsigned int poff = 0; int totalChunks = 0;
    auto addm = [&](const float* s, int kc) {
        pa.src[nm] = s; pa.doff[nm] = poff; pa.nchunk[nm] = kc;
        poff += (unsigned int)kc * 4096; totalChunks += kc; ++nm;
    };
    for (int l = 0; l < 4; ++l) {
        addm(mW1 + (size_t)l * 257 * 128, 8);
        addm(mW2 + (size_t)l * 128 * 128, 4);
        addm(cW1 + (size_t)l * 128 * 128, 4);
        addm(nW1 + (size_t)l * 256 * 128, 8);
        addm(nW2 + (size_t)l * 128 * 128, 4);
    }
    addm(oW1, 4);
    addm(oW2, 4);
    addm(embW, 2);
    pa.nmat = nm;

    const unsigned int LSTRIDE = 28 * 4096;
    const __hip_bfloat16* oW1p  = packed + (size_t)4 * LSTRIDE;
    const __hip_bfloat16* oW2p  = packed + (size_t)4 * LSTRIDE + 4 * 4096;
    const __hip_bfloat16* embWp = packed + (size_t)4 * LSTRIDE + 8 * 4096;

    hipMemcpyAsync(posb, pos, (size_t)N * 3 * sizeof(float),
                   hipMemcpyDeviceToDevice, stream);
    repack_kernel<<<totalChunks, 256, 0, stream>>>(pa, packed);

    const int scanBlocks = (N + 4095) / 4096;
    hipMemsetAsync(cnt, 0, (size_t)N * sizeof(int), stream);
    hist_kernel<<<(Etot + 255) / 256, 256, 0, stream>>>(ei, cnt, E, N);
    scan_block_kernel<<<scanBlocks, 256, 0, stream>>>(cnt, soff, part, N);
    scan_part_kernel<<<1, 64, 0, stream>>>(part, scanBlocks);
    scan_add_kernel<<<scanBlocks, 256, 0, stream>>>(soff, part, N);
    scatter_kernel<<<(Etot + 255) / 256, 256, 0, stream>>>(ei, soff, esrc, edst, E, N);

    const int nodeBlocks64 = (N + 63) / 64;
    const int edgeBlocks   = (Etot + 63) / 64;

    // fused embed + layer-0 precompute
    embed_pre_kernel<<<nodeBlocks64, 256, 0, stream>>>(
        hin, embWp, embb,
        packed, mb1, packed + 12 * 4096,
        cb1, cW2, cb2,
        hbuf, h16, U16, V16, wnum, N);

    for (int l = 0; l < 4; ++l) {
        hipMemsetAsync(aggb, 0, (size_t)N * 128 * sizeof(float), stream);
        hipMemsetAsync(pdel, 0, (size_t)N * 3 * sizeof(float), stream);
        const __hip_bfloat16* lp = packed + (size_t)l * LSTRIDE;
        edge_kernel<<<edgeBlocks, 256, 0, stream>>>(
            U16, V16, wnum, posb, esrc, edst,
            mW1 + (size_t)l * 257 * 128 + 256 * 128,
            lp + 8 * 4096, mb2 + l * 128,
            aggb, pdel, Etot);
        const int ln = (l < 3) ? (l + 1) : l;
        const __hip_bfloat16* lpn = packed + (size_t)ln * LSTRIDE;
        node_mfma_kernel<<<nodeBlocks64, 256, 0, stream>>>(
            hbuf, h16, aggb, posb, pdel,
            lp + 16 * 4096, nb1 + l * 128,
            lp + 24 * 4096, nb2 + l * 128,
            lpn, mb1 + (size_t)ln * 128,
            lpn + 12 * 4096, cb1 + (size_t)ln * 128,
            cW2 + (size_t)ln * 128, cb2 + ln,
            U16, V16, wnum,
            oW1p, ob1, oW2p, ob2, outp,
            N, (l < 3) ? 1 : 2);
    }

    hipMemcpyAsync(outp + (size_t)N * 128, posb, (size_t)N * 3 * sizeof(float),
                   hipMemcpyDeviceToDevice, stream);
}

// Round 10
// 1024.959 us; speedup vs baseline: 1.0514x; 1.0514x over previous
//
#include <hip/hip_runtime.h>
#include <hip/hip_bf16.h>

#define EPSV 1e-8f

typedef short bf16x8 __attribute__((ext_vector_type(8)));
typedef float f32x4  __attribute__((ext_vector_type(4)));

__device__ __forceinline__ float silu_f(float x) {
    return x * __builtin_amdgcn_rcpf(1.0f + __expf(-x));
}
__device__ __forceinline__ float bf2f(short v) {
    return __uint_as_float(((unsigned int)(unsigned short)v) << 16);
}
__device__ __forceinline__ short f2bfs(float f) {
    __hip_bfloat16 h = __float2bfloat16(f);
    return *(short*)&h;
}

// ======================= weight repack: f32 KxN(row-major, N=128) -> bf16 MFMA-B frags
#define MAXM 24
struct PackArgs {
    const float* src[MAXM];
    unsigned int doff[MAXM];
    int nchunk[MAXM];
    int nmat;
};

__global__ __launch_bounds__(256) void repack_kernel(PackArgs pa, __hip_bfloat16* base)
{
    int bid = blockIdx.x;
    int m = 0, c = bid;
    while (m < pa.nmat && c >= pa.nchunk[m]) { c -= pa.nchunk[m]; ++m; }
    const float* src = pa.src[m];
    __hip_bfloat16* dst = base + pa.doff[m] + (size_t)c * 4096;
    for (int o = threadIdx.x; o < 4096; o += 256) {
        int j = o & 7, n = (o >> 3) & 127, g = o >> 10;
        dst[o] = __float2bfloat16(src[(size_t)(c * 32 + g * 8 + j) * 128 + n]);
    }
}

// ======================= edge dst-sort: histogram -> scan -> scatter
__global__ __launch_bounds__(256) void hist_kernel(
    const int* __restrict__ ei, int* __restrict__ cnt, int E, int N)
{
    int e = blockIdx.x * 256 + threadIdx.x;
    int Etot = E + N;
    if (e < Etot) {
        int d = (e < E) ? ei[E + e] : (e - E);
        atomicAdd(&cnt[d], 1);
    }
}

__global__ __launch_bounds__(256) void scan_block_kernel(
    const int* __restrict__ cnt, int* __restrict__ off, int* __restrict__ part, int n)
{
    __shared__ int sdata[256];
    const int tid = threadIdx.x;
    const int base = blockIdx.x * 4096 + tid * 16;
    int loc[16]; int s = 0;
    #pragma unroll
    for (int i = 0; i < 16; ++i) {
        int idx = base + i;
        int v = (idx < n) ? cnt[idx] : 0;
        loc[i] = s; s += v;
    }
    sdata[tid] = s;
    __syncthreads();
    for (int st = 1; st < 256; st <<= 1) {
        int v = (tid >= st) ? sdata[tid - st] : 0;
        __syncthreads();
        sdata[tid] += v;
        __syncthreads();
    }
    int texc = (tid > 0) ? sdata[tid - 1] : 0;
    #pragma unroll
    for (int i = 0; i < 16; ++i) {
        int idx = base + i;
        if (idx < n) off[idx] = texc + loc[i];
    }
    if (tid == 255) part[blockIdx.x] = sdata[255];
}

__global__ void scan_part_kernel(int* part, int np)
{
    if (threadIdx.x == 0 && blockIdx.x == 0) {
        int run = 0;
        for (int i = 0; i < np; ++i) { int v = part[i]; part[i] = run; run += v; }
    }
}

__global__ __launch_bounds__(256) void scan_add_kernel(
    int* __restrict__ off, const int* __restrict__ part, int n)
{
    int idx = blockIdx.x * 4096 + threadIdx.x * 16;
    int p = part[blockIdx.x];
    #pragma unroll
    for (int i = 0; i < 16; ++i)
        if (idx + i < n) off[idx + i] += p;
}

__global__ __launch_bounds__(256) void scatter_kernel(
    const int* __restrict__ ei, int* __restrict__ off,
    int* __restrict__ esrc, int* __restrict__ edst, int E, int N)
{
    int e = blockIdx.x * 256 + threadIdx.x;
    int Etot = E + N;
    if (e < Etot) {
        int s, d;
        if (e < E) { s = ei[e]; d = ei[E + e]; }
        else       { s = d = e - E; }
        int p = atomicAdd(&off[d], 1);
        esrc[p] = s; edst[p] = d;
    }
}

// ======================= core MFMA tile GEMM (A in LDS, B packed global; 4 waves x 32 cols)
template<int LDA>
__device__ __forceinline__ void mfma_gemm(const __hip_bfloat16 (*At)[LDA], int acol0,
                                          const __hip_bfloat16* __restrict__ Bp,
                                          int kchunks, int w, int lane, f32x4 acc[4][2])
{
    const int ar = lane & 15, g = lane >> 4;
    const int bc = w * 32 + (lane & 15);
    for (int c = 0; c < kchunks; ++c) {
        const int ao = acol0 + c * 32 + g * 8;
        bf16x8 a0 = *(const bf16x8*)&At[ar +  0][ao];
        bf16x8 a1 = *(const bf16x8*)&At[ar + 16][ao];
        bf16x8 a2 = *(const bf16x8*)&At[ar + 32][ao];
        bf16x8 a3 = *(const bf16x8*)&At[ar + 48][ao];
        const __hip_bfloat16* bb = Bp + ((size_t)((c * 4 + g) * 128) + bc) * 8;
        bf16x8 b0 = *(const bf16x8*)(bb);
        bf16x8 b1 = *(const bf16x8*)(bb + 128);
        acc[0][0] = __builtin_amdgcn_mfma_f32_16x16x32_bf16(a0, b0, acc[0][0], 0, 0, 0);
        acc[1][0] = __builtin_amdgcn_mfma_f32_16x16x32_bf16(a1, b0, acc[1][0], 0, 0, 0);
        acc[2][0] = __builtin_amdgcn_mfma_f32_16x16x32_bf16(a2, b0, acc[2][0], 0, 0, 0);
        acc[3][0] = __builtin_amdgcn_mfma_f32_16x16x32_bf16(a3, b0, acc[3][0], 0, 0, 0);
        acc[0][1] = __builtin_amdgcn_mfma_f32_16x16x32_bf16(a0, b1, acc[0][1], 0, 0, 0);
        acc[1][1] = __builtin_amdgcn_mfma_f32_16x16x32_bf16(a1, b1, acc[1][1], 0, 0, 0);
        acc[2][1] = __builtin_amdgcn_mfma_f32_16x16x32_bf16(a2, b1, acc[2][1], 0, 0, 0);
        acc[3][1] = __builtin_amdgcn_mfma_f32_16x16x32_bf16(a3, b1, acc[3][1], 0, 0, 0);
    }
}

__device__ __forceinline__ void zacc(f32x4 acc[4][2]) {
    #pragma unroll
    for (int r = 0; r < 4; ++r)
        #pragma unroll
        for (int c = 0; c < 2; ++c) acc[r][c] = (f32x4){0.f, 0.f, 0.f, 0.f};
}

// ======================= fused embed + layer-0 precompute (all MFMA)
__global__ __launch_bounds__(256) void embed_pre_kernel(
    const float* __restrict__ hin,
    const __hip_bfloat16* __restrict__ embWp, const float* __restrict__ embb,
    const __hip_bfloat16* __restrict__ W1p, const float* __restrict__ b1,
    const __hip_bfloat16* __restrict__ cW1p,
    const float* __restrict__ cb1, const float* __restrict__ cW2,
    const float* __restrict__ cb2,
    float* __restrict__ hbuf, __hip_bfloat16* __restrict__ h16,
    __hip_bfloat16* __restrict__ U16, __hip_bfloat16* __restrict__ V16,
    float* __restrict__ wnum, int N)
{
    __shared__ __hip_bfloat16 a_e[64][72];
    __shared__ __hip_bfloat16 a_h[64][136];
    __shared__ float redw[64][4];
    const int t = threadIdx.x;
    const int nb = blockIdx.x * 64;
    const int lane = t & 63, w = t >> 6, g = lane >> 4, l15 = lane & 15;

    #pragma unroll
    for (int it = 0; it < 2; ++it) {
        int flat = t + 256 * it;
        int c8 = flat & 7, e = flat >> 3;
        int node = nb + e; if (node >= N) node = N - 1;
        const float* hp = hin + (size_t)node * 64 + c8 * 8;
        float4 v0 = *(const float4*)hp, v1 = *(const float4*)(hp + 4);
        bf16x8 r;
        r[0] = f2bfs(v0.x); r[1] = f2bfs(v0.y); r[2] = f2bfs(v0.z); r[3] = f2bfs(v0.w);
        r[4] = f2bfs(v1.x); r[5] = f2bfs(v1.y); r[6] = f2bfs(v1.z); r[7] = f2bfs(v1.w);
        *(bf16x8*)(&a_e[e][c8 * 8]) = r;
    }
    __syncthreads();

    const int colA = w * 32 + l15, colB = colA + 16;
    f32x4 acc[4][2];

    zacc(acc);
    mfma_gemm<72>(a_e, 0, embWp, 2, w, lane, acc);
    {
        float bA = embb[colA], bB = embb[colB];
        #pragma unroll
        for (int r = 0; r < 4; ++r)
            #pragma unroll
            for (int q = 0; q < 4; ++q) {
                int row = r * 16 + g * 4 + q;
                int node = nb + row;
                float va = acc[r][0][q] + bA, vb = acc[r][1][q] + bB;
                __hip_bfloat16 ha = __float2bfloat16(va), hb = __float2bfloat16(vb);
                a_h[row][colA] = ha; a_h[row][colB] = hb;
                if (node < N) {
                    size_t off = (size_t)node * 128;
                    hbuf[off + colA] = va; hbuf[off + colB] = vb;
                    h16[off + colA] = ha; h16[off + colB] = hb;
                }
            }
    }
    __syncthreads();

    zacc(acc);
    mfma_gemm<136>(a_h, 0, W1p, 4, w, lane, acc);
    {
        float bA = b1[colA], bB = b1[colB];
        #pragma unroll
        for (int r = 0; r < 4; ++r)
            #pragma unroll
            for (int q = 0; q < 4; ++q) {
                int node = nb + r * 16 + g * 4 + q;
                if (node < N) {
                    U16[(size_t)node * 128 + colA] = __float2bfloat16(acc[r][0][q] + bA);
                    U16[(size_t)node * 128 + colB] = __float2bfloat16(acc[r][1][q] + bB);
                }
            }
    }
    zacc(acc);
    mfma_gemm<136>(a_h, 0, W1p + 4 * 4096, 4, w, lane, acc);
    #pragma unroll
    for (int r = 0; r < 4; ++r)
        #pragma unroll
        for (int q = 0; q < 4; ++q) {
            int node = nb + r * 16 + g * 4 + q;
            if (node < N) {
                V16[(size_t)node * 128 + colA] = __float2bfloat16(acc[r][0][q]);
                V16[(size_t)node * 128 + colB] = __float2bfloat16(acc[r][1][q]);
            }
        }
    zacc(acc);
    mfma_gemm<136>(a_h, 0, cW1p, 4, w, lane, acc);
    {
        float cb1A = cb1[colA], cb1B = cb1[colB];
        float wA = cW2[colA], wB = cW2[colB];
        #pragma unroll
        for (int r = 0; r < 4; ++r)
            #pragma unroll
            for (int q = 0; q < 4; ++q) {
                float p = silu_f(acc[r][0][q] + cb1A) * wA
                        + silu_f(acc[r][1][q] + cb1B) * wB;
                p += __shfl_xor(p, 1);
                p += __shfl_xor(p, 2);
                p += __shfl_xor(p, 4);
                p += __shfl_xor(p, 8);
                if (l15 == 0) redw[r * 16 + g * 4 + q][w] = p;
            }
    }
    __syncthreads();
    if (t < 64 && nb + t < N)
        wnum[nb + t] = redw[t][0] + redw[t][1] + redw[t][2] + redw[t][3] + cb2[0];
}

// ======================= per-layer edge kernel (64 edges / 256 threads,
// register gather-prefetch before the metadata barrier; round-7 reduce)
__global__ __launch_bounds__(256) void edge_kernel(
    const __hip_bfloat16* __restrict__ U16, const __hip_bfloat16* __restrict__ V16,
    const float* __restrict__ wnum, const float* __restrict__ posb,
    const int* __restrict__ esrc, const int* __restrict__ edst,
    const float* __restrict__ W1tail,
    const __hip_bfloat16* __restrict__ W2p, const float* __restrict__ b2,
    float* __restrict__ agg, float* __restrict__ pdel, int Etot)
{
    __shared__ __hip_bfloat16 m1s[64][136];    // reused for m2 after GEMM2
    __shared__ int   dstl[64];
    __shared__ float relt[3][64], distl[64], wscl[64];

    const int t = threadIdx.x;
    const int eb = blockIdx.x * 64;
    const int lane = t & 63, w = t >> 6, g = lane >> 4, l15 = lane & 15;

    // --- phase 0: per-thread index load + U/V gather issue (no barrier dependence)
    const int c8 = t & 15, row0 = t >> 4;
    bf16x8 uvr[4], vvr[4];
    int dval[4];
    #pragma unroll
    for (int j = 0; j < 4; ++j) {
        int row = row0 + 16 * j;
        int e = eb + row;
        int s = 0, d = 0;
        if (e < Etot) { s = esrc[e]; d = edst[e]; dval[j] = 1; }
        else          { dval[j] = 0; }
        uvr[j] = *(const bf16x8*)(U16 + (size_t)d * 128 + c8 * 8);
        vvr[j] = *(const bf16x8*)(V16 + (size_t)s * 128 + c8 * 8);
    }

    // --- wave 0: metadata (overlaps with in-flight gathers of other waves)
    if (t < 64) {
        int e = eb + t;
        int s = 0, d = -1;
        if (e < Etot) { s = esrc[e]; d = edst[e]; }
        dstl[t] = d;
        int dd = (d < 0) ? 0 : d;
        float rx = posb[3 * s + 0] - posb[3 * dd + 0];
        float ry = posb[3 * s + 1] - posb[3 * dd + 1];
        float rz = posb[3 * s + 2] - posb[3 * dd + 2];
        float dist = sqrtf(rx * rx + ry * ry + rz * rz);
        relt[0][t] = rx; relt[1][t] = ry; relt[2][t] = rz;
        distl[t] = dist;
        wscl[t] = wnum[s] * __builtin_amdgcn_rcpf(dist + EPSV);
    }
    __syncthreads();

    // pdel scatter early
    if (t < 192) {
        int e = t / 3, comp = t % 3;
        if (dstl[e] >= 0)
            atomicAdd(&pdel[(size_t)dstl[e] * 3 + comp], wscl[e] * relt[comp][e]);
    }

    // --- m1 = silu(U[dst](b1 folded) + V[src] + dist*wt) from prefetched registers
    {
        float wt[8];
        *(float4*)&wt[0] = *(const float4*)(W1tail + c8 * 8);
        *(float4*)&wt[4] = *(const float4*)(W1tail + c8 * 8 + 4);
        #pragma unroll
        for (int j = 0; j < 4; ++j) {
            int row = row0 + 16 * j;
            bf16x8 res;
            if (dval[j]) {
                float dv = distl[row];
                #pragma unroll
                for (int k = 0; k < 8; ++k) {
                    float x = bf2f(uvr[j][k]) + bf2f(vvr[j][k]) + dv * wt[k];
                    res[k] = f2bfs(silu_f(x));
                }
            } else {
                #pragma unroll
                for (int k = 0; k < 8; ++k) res[k] = 0;
            }
            *(bf16x8*)(&m1s[row][c8 * 8]) = res;
        }
    }
    __syncthreads();

    // --- GEMM2: m2 = m1 @ W2
    const int colA = w * 32 + l15, colB = colA + 16;
    f32x4 acc[4][2];
    zacc(acc);
    mfma_gemm<136>(m1s, 0, W2p, 4, w, lane, acc);
    __syncthreads();   // all m1s reads done; safe to overwrite with m2

    // --- write silu(m2 + b2) back into the same LDS (bf16)
    {
        float b2a = b2[colA], b2b = b2[colB];
        #pragma unroll
        for (int r = 0; r < 4; ++r)
            #pragma unroll
            for (int q = 0; q < 4; ++q) {
                int row = r * 16 + g * 4 + q;
                m1s[row][colA] = __float2bfloat16(silu_f(acc[r][0][q] + b2a));
                m1s[row][colB] = __float2bfloat16(silu_f(acc[r][1][q] + b2b));
            }
    }
    __syncthreads();

    // --- segmented reduction (round-7 proven): 1 col/thread, 2 halves x 32 rows
    {
        int col = t & 127, half = t >> 7;
        int r0 = half * 32;
        float a = 0.f;
        int cur = dstl[r0];
        #pragma unroll 4
        for (int r = r0; r < r0 + 32; ++r) {
            int d = dstl[r];
            if (d != cur) {
                if (cur >= 0) atomicAdd(&agg[(size_t)cur * 128 + col], a);
                a = 0.f; cur = d;
            }
            if (d >= 0) a += bf2f(*(const short*)&m1s[r][col]);
        }
        if (cur >= 0) atomicAdd(&agg[(size_t)cur * 128 + col], a);
    }
}

// ======================= per-layer node kernel
// mode 1: fused precompute for next layer; mode 2: fused output head
__global__ __launch_bounds__(256) void node_mfma_kernel(
    float* __restrict__ hbuf, __hip_bfloat16* __restrict__ h16,
    const float* __restrict__ agg,
    float* __restrict__ posb, const float* __restrict__ pdel,
    const __hip_bfloat16* __restrict__ W1p, const float* __restrict__ b1,
    const __hip_bfloat16* __restrict__ W2p, const float* __restrict__ b2,
    const __hip_bfloat16* __restrict__ nxtW1p, const float* __restrict__ nxt_b1,
    const __hip_bfloat16* __restrict__ nxt_cW1p, const float* __restrict__ nxt_cb1,
    const float* __restrict__ nxt_cW2, const float* __restrict__ nxt_cb2,
    __hip_bfloat16* __restrict__ U16, __hip_bfloat16* __restrict__ V16,
    float* __restrict__ wnum,
    const __hip_bfloat16* __restrict__ oW1p, const float* __restrict__ ob1,
    const __hip_bfloat16* __restrict__ oW2p, const float* __restrict__ ob2,
    float* __restrict__ outp,
    int N, int mode)
{
    __shared__ __hip_bfloat16 a_t[64][264];   // [h | agg] then [newh | agg]
    __shared__ __hip_bfloat16 us[64][136];
    __shared__ float redw[64][4];
    const int t = threadIdx.x;
    const int nb = blockIdx.x * 64;
    const int lane = t & 63, w = t >> 6, g = lane >> 4, l15 = lane & 15;

    #pragma unroll
    for (int it = 0; it < 4; ++it) {
        int flat = t + 256 * it;
        int c = flat & 15, e = flat >> 4;
        int node = nb + e; if (node >= N) node = N - 1;
        *(int4*)(&a_t[e][c * 8]) = *(const int4*)(h16 + (size_t)node * 128 + c * 8);
    }
    #pragma unroll
    for (int it = 0; it < 8; ++it) {
        int flat = t + 256 * it;
        int c = flat & 31, e = flat >> 5;
        int node = nb + e; if (node >= N) node = N - 1;
        float4 v = *(const float4*)(agg + (size_t)node * 128 + c * 4);
        __hip_bfloat16* p = &a_t[e][128 + c * 4];
        p[0] = __float2bfloat16(v.x); p[1] = __float2bfloat16(v.y);
        p[2] = __float2bfloat16(v.z); p[3] = __float2bfloat16(v.w);
    }
    __syncthreads();

    const int colA = w * 32 + l15, colB = colA + 16;
    f32x4 acc[4][2];

    zacc(acc);
    mfma_gemm<264>(a_t, 0, W1p, 8, w, lane, acc);
    {
        float b1a = b1[colA], b1b = b1[colB];
        #pragma unroll
        for (int r = 0; r < 4; ++r)
            #pragma unroll
            for (int q = 0; q < 4; ++q) {
                int row = r * 16 + g * 4 + q;
                us[row][colA] = __float2bfloat16(silu_f(acc[r][0][q] + b1a));
                us[row][colB] = __float2bfloat16(silu_f(acc[r][1][q] + b1b));
            }
    }
    __syncthreads();

    zacc(acc);
    mfma_gemm<136>(us, 0, W2p, 4, w, lane, acc);
    {
        float b2a = b2[colA], b2b = b2[colB];
        #pragma unroll
        for (int r = 0; r < 4; ++r)
            #pragma unroll
            for (int q = 0; q < 4; ++q) {
                int row = r * 16 + g * 4 + q;
                int node = nb + row;
                if (node < N) {
                    size_t off = (size_t)node * 128;
                    float va = hbuf[off + colA] + acc[r][0][q] + b2a;
                    float vb = hbuf[off + colB] + acc[r][1][q] + b2b;
                    hbuf[off + colA] = va; hbuf[off + colB] = vb;
                    __hip_bfloat16 ha = __float2bfloat16(va), hb = __float2bfloat16(vb);
                    h16[off + colA] = ha; h16[off + colB] = hb;
                    a_t[row][colA] = ha; a_t[row][colB] = hb;
                } else {
                    a_t[row][colA] = __float2bfloat16(0.f);
                    a_t[row][colB] = __float2bfloat16(0.f);
                }
            }
    }
    if (t < 192) {
        int e = t / 3, comp = t % 3;
        int node = nb + e;
        if (node < N) posb[3 * node + comp] += pdel[3 * node + comp];
    }

    if (mode == 0) return;
    __syncthreads();   // newh staged in a_t[.][0..127]; all us reads done

    if (mode == 2) {
        // fused output head: out = silu(newh@oW1+ob1)@oW2 + ob2
        zacc(acc);
        mfma_gemm<264>(a_t, 0, oW1p, 4, w, lane, acc);
        {
            float b1a = ob1[colA], b1b = ob1[colB];
            #pragma unroll
            for (int r = 0; r < 4; ++r)
                #pragma unroll
                for (int q = 0; q < 4; ++q) {
                    int row = r * 16 + g * 4 + q;
                    us[row][colA] = __float2bfloat16(silu_f(acc[r][0][q] + b1a));
                    us[row][colB] = __float2bfloat16(silu_f(acc[r][1][q] + b1b));
                }
        }
        __syncthreads();
        zacc(acc);
        mfma_gemm<136>(us, 0, oW2p, 4, w, lane, acc);
        {
            float b2a = ob2[colA], b2b = ob2[colB];
            #pragma unroll
            for (int r = 0; r < 4; ++r)
                #pragma unroll
                for (int q = 0; q < 4; ++q) {
                    int row = r * 16 + g * 4 + q;
                    int node = nb + row;
                    if (node < N) {
                        outp[(size_t)node * 128 + colA] = acc[r][0][q] + b2a;
                        outp[(size_t)node * 128 + colB] = acc[r][1][q] + b2b;
                    }
                }
        }
        return;
    }

    // mode 1: precompute for next layer
    zacc(acc);
    mfma_gemm<264>(a_t, 0, nxtW1p, 4, w, lane, acc);
    {
        float bA = nxt_b1[colA], bB = nxt_b1[colB];
        #pragma unroll
        for (int r = 0; r < 4; ++r)
            #pragma unroll
            for (int q = 0; q < 4; ++q) {
                int node = nb + r * 16 + g * 4 + q;
                if (node < N) {
                    U16[(size_t)node * 128 + colA] = __float2bfloat16(acc[r][0][q] + bA);
                    U16[(size_t)node * 128 + colB] = __float2bfloat16(acc[r][1][q] + bB);
                }
            }
    }
    zacc(acc);
    mfma_gemm<264>(a_t, 0, nxtW1p + 4 * 4096, 4, w, lane, acc);
    #pragma unroll
    for (int r = 0; r < 4; ++r)
        #pragma unroll
        for (int q = 0; q < 4; ++q) {
            int node = nb + r * 16 + g * 4 + q;
            if (node < N) {
                V16[(size_t)node * 128 + colA] = __float2bfloat16(acc[r][0][q]);
                V16[(size_t)node * 128 + colB] = __float2bfloat16(acc[r][1][q]);
            }
        }
    zacc(acc);
    mfma_gemm<264>(a_t, 0, nxt_cW1p, 4, w, lane, acc);
    {
        float cb1A = nxt_cb1[colA], cb1B = nxt_cb1[colB];
        float wA = nxt_cW2[colA], wB = nxt_cW2[colB];
        #pragma unroll
        for (int r = 0; r < 4; ++r)
            #pragma unroll
            for (int q = 0; q < 4; ++q) {
                float p = silu_f(acc[r][0][q] + cb1A) * wA
                        + silu_f(acc[r][1][q] + cb1B) * wB;
                p += __shfl_xor(p, 1);
                p += __shfl_xor(p, 2);
                p += __shfl_xor(p, 4);
                p += __shfl_xor(p, 8);
                if (l15 == 0) redw[r * 16 + g * 4 + q][w] = p;
            }
    }
    __syncthreads();
    if (t < 64 && nb + t < N)
        wnum[nb + t] = redw[t][0] + redw[t][1] + redw[t][2] + redw[t][3] + nxt_cb2[0];
}

// =======================
extern "C" void kernel_launch(void* const* d_in, const int* in_sizes, int n_in,
                              void* d_out, int out_size, void* d_ws, size_t ws_size,
                              hipStream_t stream)
{
    const float* hin  = (const float*)d_in[0];
    const float* pos  = (const float*)d_in[1];
    const int*   ei   = (const int*)d_in[2];
    const float* embW = (const float*)d_in[3];
    const float* embb = (const float*)d_in[4];
    const float* mW1  = (const float*)d_in[5];
    const float* mb1  = (const float*)d_in[6];
    const float* mW2  = (const float*)d_in[7];
    const float* mb2  = (const float*)d_in[8];
    const float* cW1  = (const float*)d_in[9];
    const float* cb1  = (const float*)d_in[10];
    const float* cW2  = (const float*)d_in[11];
    const float* cb2  = (const float*)d_in[12];
    const float* nW1  = (const float*)d_in[13];
    const float* nb1  = (const float*)d_in[14];
    const float* nW2  = (const float*)d_in[15];
    const float* nb2  = (const float*)d_in[16];
    const float* oW1  = (const float*)d_in[17];
    const float* ob1  = (const float*)d_in[18];
    const float* oW2  = (const float*)d_in[19];
    const float* ob2  = (const float*)d_in[20];

    const int N = in_sizes[0] / 64;
    const int E = in_sizes[2] / 2;
    const int Etot = E + N;

    float* hbuf = (float*)d_ws;                                  // N*128 f32
    float* aggb = hbuf + (size_t)N * 128;                        // N*128 f32
    float* posb = aggb + (size_t)N * 128;                        // N*3
    float* pdel = posb + (size_t)N * 3;                          // N*3
    float* wnum = pdel + (size_t)N * 3;                          // N f32
    __hip_bfloat16* h16 = (__hip_bfloat16*)(wnum + N);           // N*128 bf16
    __hip_bfloat16* U16 = h16 + (size_t)N * 128;                 // N*128 bf16
    __hip_bfloat16* V16 = U16 + (size_t)N * 128;                 // N*128 bf16
    __hip_bfloat16* packed = V16 + (size_t)N * 128;              // 122*4096 bf16
    int* cnt  = (int*)(packed + 122 * 4096);                     // N
    int* soff = cnt + N;                                         // N
    int* part = soff + N;                                        // 64
    int* esrc = part + 64;                                       // Etot
    int* edst = esrc + Etot;                                     // Etot
    float* outp = (float*)d_out;

    PackArgs pa;
    int nm = 0; unsigned int poff = 0; int totalChunks = 0;
    auto addm = [&](const float* s, int kc) {
        pa.src[nm] = s; pa.doff[nm] = poff; pa.nchunk[nm] = kc;
        poff += (unsigned int)kc * 4096; totalChunks += kc; ++nm;
    };
    for (int l = 0; l < 4; ++l) {
        addm(mW1 + (size_t)l * 257 * 128, 8);
        addm(mW2 + (size_t)l * 128 * 128, 4);
        addm(cW1 + (size_t)l * 128 * 128, 4);
        addm(nW1 + (size_t)l * 256 * 128, 8);
        addm(nW2 + (size_t)l * 128 * 128, 4);
    }
    addm(oW1, 4);
    addm(oW2, 4);
    addm(embW, 2);
    pa.nmat = nm;

    const unsigned int LSTRIDE = 28 * 4096;
    const __hip_bfloat16* oW1p  = packed + (size_t)4 * LSTRIDE;
    const __hip_bfloat16* oW2p  = packed + (size_t)4 * LSTRIDE + 4 * 4096;
    const __hip_bfloat16* embWp = packed + (size_t)4 * LSTRIDE + 8 * 4096;

    hipMemcpyAsync(posb, pos, (size_t)N * 3 * sizeof(float),
                   hipMemcpyDeviceToDevice, stream);
    repack_kernel<<<totalChunks, 256, 0, stream>>>(pa, packed);

    const int scanBlocks = (N + 4095) / 4096;
    hipMemsetAsync(cnt, 0, (size_t)N * sizeof(int), stream);
    hist_kernel<<<(Etot + 255) / 256, 256, 0, stream>>>(ei, cnt, E, N);
    scan_block_kernel<<<scanBlocks, 256, 0, stream>>>(cnt, soff, part, N);
    scan_part_kernel<<<1, 64, 0, stream>>>(part, scanBlocks);
    scan_add_kernel<<<scanBlocks, 256, 0, stream>>>(soff, part, N);
    scatter_kernel<<<(Etot + 255) / 256, 256, 0, stream>>>(ei, soff, esrc, edst, E, N);

    const int nodeBlocks64 = (N + 63) / 64;
    const int edgeBlocks   = (Etot + 63) / 64;

    embed_pre_kernel<<<nodeBlocks64, 256, 0, stream>>>(
        hin, embWp, embb,
        packed, mb1, packed + 12 * 4096,
        cb1, cW2, cb2,
        hbuf, h16, U16, V16, wnum, N);

    for (int l = 0; l < 4; ++l) {
        hipMemsetAsync(aggb, 0, (size_t)N * 128 * sizeof(float), stream);
        hipMemsetAsync(pdel, 0, (size_t)N * 3 * sizeof(float), stream);
        const __hip_bfloat16* lp = packed + (size_t)l * LSTRIDE;
        edge_kernel<<<edgeBlocks, 256, 0, stream>>>(
            U16, V16, wnum, posb, esrc, edst,
            mW1 + (size_t)l * 257 * 128 + 256 * 128,
            lp + 8 * 4096, mb2 + l * 128,
            aggb, pdel, Etot);
        const int ln = (l < 3) ? (l + 1) : l;
        const __hip_bfloat16* lpn = packed + (size_t)ln * LSTRIDE;
        node_mfma_kernel<<<nodeBlocks64, 256, 0, stream>>>(
            hbuf, h16, aggb, posb, pdel,
            lp + 16 * 4096, nb1 + l * 128,
            lp + 24 * 4096, nb2 + l * 128,
            lpn, mb1 + (size_t)ln * 128,
            lpn + 12 * 4096, cb1 + (size_t)ln * 128,
            cW2 + (size_t)ln * 128, cb2 + ln,
            U16, V16, wnum,
            oW1p, ob1, oW2p, ob2, outp,
            N, (l < 3) ? 1 : 2);
    }

    hipMemcpyAsync(outp + (size_t)N * 128, posb, (size_t)N * 3 * sizeof(float),
                   hipMemcpyDeviceToDevice, stream);
}

// Round 12
// 1003.985 us; speedup vs baseline: 1.0733x; 1.0209x over previous
//
#include <hip/hip_runtime.h>
#include <hip/hip_bf16.h>

#define EPSV 1e-8f

typedef short bf16x8 __attribute__((ext_vector_type(8)));
typedef float f32x4  __attribute__((ext_vector_type(4)));

__device__ __forceinline__ float silu_f(float x) {
    return x * __builtin_amdgcn_rcpf(1.0f + __expf(-x));
}
__device__ __forceinline__ float bf2f(short v) {
    return __uint_as_float(((unsigned int)(unsigned short)v) << 16);
}
__device__ __forceinline__ short f2bfs(float f) {
    __hip_bfloat16 h = __float2bfloat16(f);
    return *(short*)&h;
}

// ======================= weight repack: f32 KxN(row-major, N=128) -> bf16 MFMA-B frags
#define MAXM 24
struct PackArgs {
    const float* src[MAXM];
    unsigned int doff[MAXM];
    int nchunk[MAXM];
    int nmat;
};

__global__ __launch_bounds__(256) void repack_kernel(PackArgs pa, __hip_bfloat16* base)
{
    int bid = blockIdx.x;
    int m = 0, c = bid;
    while (m < pa.nmat && c >= pa.nchunk[m]) { c -= pa.nchunk[m]; ++m; }
    const float* src = pa.src[m];
    __hip_bfloat16* dst = base + pa.doff[m] + (size_t)c * 4096;
    for (int o = threadIdx.x; o < 4096; o += 256) {
        int j = o & 7, n = (o >> 3) & 127, g = o >> 10;
        dst[o] = __float2bfloat16(src[(size_t)(c * 32 + g * 8 + j) * 128 + n]);
    }
}

// ======================= edge dst-sort: histogram -> scan -> scatter
__global__ __launch_bounds__(256) void hist_kernel(
    const int* __restrict__ ei, int* __restrict__ cnt, int E, int N)
{
    int e = blockIdx.x * 256 + threadIdx.x;
    int Etot = E + N;
    if (e < Etot) {
        int d = (e < E) ? ei[E + e] : (e - E);
        atomicAdd(&cnt[d], 1);
    }
}

__global__ __launch_bounds__(256) void scan_block_kernel(
    const int* __restrict__ cnt, int* __restrict__ off, int* __restrict__ part, int n)
{
    __shared__ int sdata[256];
    const int tid = threadIdx.x;
    const int base = blockIdx.x * 4096 + tid * 16;
    int loc[16]; int s = 0;
    #pragma unroll
    for (int i = 0; i < 16; ++i) {
        int idx = base + i;
        int v = (idx < n) ? cnt[idx] : 0;
        loc[i] = s; s += v;
    }
    sdata[tid] = s;
    __syncthreads();
    for (int st = 1; st < 256; st <<= 1) {
        int v = (tid >= st) ? sdata[tid - st] : 0;
        __syncthreads();
        sdata[tid] += v;
        __syncthreads();
    }
    int texc = (tid > 0) ? sdata[tid - 1] : 0;
    #pragma unroll
    for (int i = 0; i < 16; ++i) {
        int idx = base + i;
        if (idx < n) off[idx] = texc + loc[i];
    }
    if (tid == 255) part[blockIdx.x] = sdata[255];
}

__global__ void scan_part_kernel(int* part, int np)
{
    if (threadIdx.x == 0 && blockIdx.x == 0) {
        int run = 0;
        for (int i = 0; i < np; ++i) { int v = part[i]; part[i] = run; run += v; }
    }
}

__global__ __launch_bounds__(256) void scan_add_kernel(
    int* __restrict__ off, const int* __restrict__ part, int n)
{
    int idx = blockIdx.x * 4096 + threadIdx.x * 16;
    int p = part[blockIdx.x];
    #pragma unroll
    for (int i = 0; i < 16; ++i)
        if (idx + i < n) off[idx + i] += p;
}

__global__ __launch_bounds__(256) void scatter_kernel(
    const int* __restrict__ ei, int* __restrict__ off,
    int* __restrict__ esrc, int* __restrict__ edst, int E, int N)
{
    int e = blockIdx.x * 256 + threadIdx.x;
    int Etot = E + N;
    if (e < Etot) {
        int s, d;
        if (e < E) { s = ei[e]; d = ei[E + e]; }
        else       { s = d = e - E; }
        int p = atomicAdd(&off[d], 1);
        esrc[p] = s; edst[p] = d;
    }
}

// ======================= core MFMA tile GEMM (A in LDS, B packed global; 4 waves x 32 cols)
template<int LDA>
__device__ __forceinline__ void mfma_gemm(const __hip_bfloat16 (*At)[LDA], int acol0,
                                          const __hip_bfloat16* __restrict__ Bp,
                                          int kchunks, int w, int lane, f32x4 acc[4][2])
{
    const int ar = lane & 15, g = lane >> 4;
    const int bc = w * 32 + (lane & 15);
    for (int c = 0; c < kchunks; ++c) {
        const int ao = acol0 + c * 32 + g * 8;
        bf16x8 a0 = *(const bf16x8*)&At[ar +  0][ao];
        bf16x8 a1 = *(const bf16x8*)&At[ar + 16][ao];
        bf16x8 a2 = *(const bf16x8*)&At[ar + 32][ao];
        bf16x8 a3 = *(const bf16x8*)&At[ar + 48][ao];
        const __hip_bfloat16* bb = Bp + ((size_t)((c * 4 + g) * 128) + bc) * 8;
        bf16x8 b0 = *(const bf16x8*)(bb);
        bf16x8 b1 = *(const bf16x8*)(bb + 128);
        acc[0][0] = __builtin_amdgcn_mfma_f32_16x16x32_bf16(a0, b0, acc[0][0], 0, 0, 0);
        acc[1][0] = __builtin_amdgcn_mfma_f32_16x16x32_bf16(a1, b0, acc[1][0], 0, 0, 0);
        acc[2][0] = __builtin_amdgcn_mfma_f32_16x16x32_bf16(a2, b0, acc[2][0], 0, 0, 0);
        acc[3][0] = __builtin_amdgcn_mfma_f32_16x16x32_bf16(a3, b0, acc[3][0], 0, 0, 0);
        acc[0][1] = __builtin_amdgcn_mfma_f32_16x16x32_bf16(a0, b1, acc[0][1], 0, 0, 0);
        acc[1][1] = __builtin_amdgcn_mfma_f32_16x16x32_bf16(a1, b1, acc[1][1], 0, 0, 0);
        acc[2][1] = __builtin_amdgcn_mfma_f32_16x16x32_bf16(a2, b1, acc[2][1], 0, 0, 0);
        acc[3][1] = __builtin_amdgcn_mfma_f32_16x16x32_bf16(a3, b1, acc[3][1], 0, 0, 0);
    }
}

__device__ __forceinline__ void zacc(f32x4 acc[4][2]) {
    #pragma unroll
    for (int r = 0; r < 4; ++r)
        #pragma unroll
        for (int c = 0; c < 2; ++c) acc[r][c] = (f32x4){0.f, 0.f, 0.f, 0.f};
}

// ======================= fused embed + layer-0 precompute (all MFMA; h kept bf16-only)
__global__ __launch_bounds__(256) void embed_pre_kernel(
    const float* __restrict__ hin,
    const __hip_bfloat16* __restrict__ embWp, const float* __restrict__ embb,
    const __hip_bfloat16* __restrict__ W1p, const float* __restrict__ b1,
    const __hip_bfloat16* __restrict__ cW1p,
    const float* __restrict__ cb1, const float* __restrict__ cW2,
    const float* __restrict__ cb2,
    __hip_bfloat16* __restrict__ h16,
    __hip_bfloat16* __restrict__ U16, __hip_bfloat16* __restrict__ V16,
    float* __restrict__ wnum, int N)
{
    __shared__ __hip_bfloat16 a_e[64][72];
    __shared__ __hip_bfloat16 a_h[64][136];
    __shared__ float redw[64][4];
    const int t = threadIdx.x;
    const int nb = blockIdx.x * 64;
    const int lane = t & 63, w = t >> 6, g = lane >> 4, l15 = lane & 15;

    #pragma unroll
    for (int it = 0; it < 2; ++it) {
        int flat = t + 256 * it;
        int c8 = flat & 7, e = flat >> 3;
        int node = nb + e; if (node >= N) node = N - 1;
        const float* hp = hin + (size_t)node * 64 + c8 * 8;
        float4 v0 = *(const float4*)hp, v1 = *(const float4*)(hp + 4);
        bf16x8 r;
        r[0] = f2bfs(v0.x); r[1] = f2bfs(v0.y); r[2] = f2bfs(v0.z); r[3] = f2bfs(v0.w);
        r[4] = f2bfs(v1.x); r[5] = f2bfs(v1.y); r[6] = f2bfs(v1.z); r[7] = f2bfs(v1.w);
        *(bf16x8*)(&a_e[e][c8 * 8]) = r;
    }
    __syncthreads();

    const int colA = w * 32 + l15, colB = colA + 16;
    f32x4 acc[4][2];

    zacc(acc);
    mfma_gemm<72>(a_e, 0, embWp, 2, w, lane, acc);
    {
        float bA = embb[colA], bB = embb[colB];
        #pragma unroll
        for (int r = 0; r < 4; ++r)
            #pragma unroll
            for (int q = 0; q < 4; ++q) {
                int row = r * 16 + g * 4 + q;
                int node = nb + row;
                float va = acc[r][0][q] + bA, vb = acc[r][1][q] + bB;
                __hip_bfloat16 ha = __float2bfloat16(va), hb = __float2bfloat16(vb);
                a_h[row][colA] = ha; a_h[row][colB] = hb;
                if (node < N) {
                    size_t off = (size_t)node * 128;
                    h16[off + colA] = ha; h16[off + colB] = hb;
                }
            }
    }
    __syncthreads();

    zacc(acc);
    mfma_gemm<136>(a_h, 0, W1p, 4, w, lane, acc);
    {
        float bA = b1[colA], bB = b1[colB];
        #pragma unroll
        for (int r = 0; r < 4; ++r)
            #pragma unroll
            for (int q = 0; q < 4; ++q) {
                int node = nb + r * 16 + g * 4 + q;
                if (node < N) {
                    U16[(size_t)node * 128 + colA] = __float2bfloat16(acc[r][0][q] + bA);
                    U16[(size_t)node * 128 + colB] = __float2bfloat16(acc[r][1][q] + bB);
                }
            }
    }
    zacc(acc);
    mfma_gemm<136>(a_h, 0, W1p + 4 * 4096, 4, w, lane, acc);
    #pragma unroll
    for (int r = 0; r < 4; ++r)
        #pragma unroll
        for (int q = 0; q < 4; ++q) {
            int node = nb + r * 16 + g * 4 + q;
            if (node < N) {
                V16[(size_t)node * 128 + colA] = __float2bfloat16(acc[r][0][q]);
                V16[(size_t)node * 128 + colB] = __float2bfloat16(acc[r][1][q]);
            }
        }
    zacc(acc);
    mfma_gemm<136>(a_h, 0, cW1p, 4, w, lane, acc);
    {
        float cb1A = cb1[colA], cb1B = cb1[colB];
        float wA = cW2[colA], wB = cW2[colB];
        #pragma unroll
        for (int r = 0; r < 4; ++r)
            #pragma unroll
            for (int q = 0; q < 4; ++q) {
                float p = silu_f(acc[r][0][q] + cb1A) * wA
                        + silu_f(acc[r][1][q] + cb1B) * wB;
                p += __shfl_xor(p, 1);
                p += __shfl_xor(p, 2);
                p += __shfl_xor(p, 4);
                p += __shfl_xor(p, 8);
                if (l15 == 0) redw[r * 16 + g * 4 + q][w] = p;
            }
    }
    __syncthreads();
    if (t < 64 && nb + t < N)
        wnum[nb + t] = redw[t][0] + redw[t][1] + redw[t][2] + redw[t][3] + cb2[0];
}

// ======================= per-layer edge kernel (round-7 exact body, 150 µs proven)
__global__ __launch_bounds__(256) void edge_kernel(
    const __hip_bfloat16* __restrict__ U16, const __hip_bfloat16* __restrict__ V16,
    const float* __restrict__ wnum, const float* __restrict__ posb,
    const int* __restrict__ esrc, const int* __restrict__ edst,
    const float* __restrict__ W1tail,
    const __hip_bfloat16* __restrict__ W2p, const float* __restrict__ b2,
    float* __restrict__ agg, float* __restrict__ pdel, int Etot)
{
    __shared__ __hip_bfloat16 m1s[64][136];    // reused for m2 after GEMM2
    __shared__ int   srcl[64], dstl[64];
    __shared__ float relt[3][64], distl[64], wscl[64];

    const int t = threadIdx.x;
    const int eb = blockIdx.x * 64;
    const int lane = t & 63, w = t >> 6, g = lane >> 4, l15 = lane & 15;

    if (t < 64) {
        int e = eb + t;
        int s = 0, d = -1;
        if (e < Etot) { s = esrc[e]; d = edst[e]; }
        srcl[t] = s; dstl[t] = d;
        int dd = (d < 0) ? 0 : d;
        float rx = posb[3 * s + 0] - posb[3 * dd + 0];
        float ry = posb[3 * s + 1] - posb[3 * dd + 1];
        float rz = posb[3 * s + 2] - posb[3 * dd + 2];
        float dist = sqrtf(rx * rx + ry * ry + rz * rz);
        relt[0][t] = rx; relt[1][t] = ry; relt[2][t] = rz;
        distl[t] = dist;
        wscl[t] = wnum[s] * __builtin_amdgcn_rcpf(dist + EPSV);
    }
    __syncthreads();

    // m1 = silu(U[dst] (b1 folded) + V[src] + dist*wt)
    #pragma unroll
    for (int j = 0; j < 4; ++j) {
        int f = t + 256 * j;              // 1024 = 64 rows x 16 octets
        int c8 = f & 15, row = f >> 4;
        bf16x8 res;
        if (dstl[row] >= 0) {
            int s = srcl[row], d = dstl[row];
            bf16x8 uv = *(const bf16x8*)(U16 + (size_t)d * 128 + c8 * 8);
            bf16x8 vv = *(const bf16x8*)(V16 + (size_t)s * 128 + c8 * 8);
            float wt[8];
            *(float4*)&wt[0] = *(const float4*)(W1tail + c8 * 8);
            *(float4*)&wt[4] = *(const float4*)(W1tail + c8 * 8 + 4);
            float dv = distl[row];
            #pragma unroll
            for (int k = 0; k < 8; ++k) {
                float x = bf2f(uv[k]) + bf2f(vv[k]) + dv * wt[k];
                res[k] = f2bfs(silu_f(x));
            }
        } else {
            #pragma unroll
            for (int k = 0; k < 8; ++k) res[k] = 0;
        }
        *(bf16x8*)(&m1s[row][c8 * 8]) = res;
    }
    __syncthreads();

    // GEMM2: m2 = m1 @ W2
    const int colA = w * 32 + l15, colB = colA + 16;
    f32x4 acc[4][2];
    zacc(acc);
    mfma_gemm<136>(m1s, 0, W2p, 4, w, lane, acc);
    __syncthreads();   // all m1s reads done; safe to overwrite with m2

    // write silu(m2 + b2) back into the same LDS (bf16)
    {
        float b2a = b2[colA], b2b = b2[colB];
        #pragma unroll
        for (int r = 0; r < 4; ++r)
            #pragma unroll
            for (int q = 0; q < 4; ++q) {
                int row = r * 16 + g * 4 + q;
                m1s[row][colA] = __float2bfloat16(silu_f(acc[r][0][q] + b2a));
                m1s[row][colB] = __float2bfloat16(silu_f(acc[r][1][q] + b2b));
            }
    }
    __syncthreads();

    // segmented reduction by dst (rows sorted): one atomic per (segment, col)
    {
        int col = t & 127, half = t >> 7;
        int r0 = half * 32;
        float a = 0.f;
        int cur = dstl[r0];
        #pragma unroll 4
        for (int r = r0; r < r0 + 32; ++r) {
            int d = dstl[r];
            if (d != cur) {
                if (cur >= 0) atomicAdd(&agg[(size_t)cur * 128 + col], a);
                a = 0.f; cur = d;
            }
            if (d >= 0) a += bf2f(*(const short*)&m1s[r][col]);
        }
        if (cur >= 0) atomicAdd(&agg[(size_t)cur * 128 + col], a);
    }

    // pdel scatter (per-edge, small)
    if (t < 192) {
        int e = t / 3, comp = t % 3;
        if (dstl[e] >= 0)
            atomicAdd(&pdel[(size_t)dstl[e] * 3 + comp], wscl[e] * relt[comp][e]);
    }
}

// ======================= per-layer node kernel (h bf16-only residual)
// mode 1: fused precompute for next layer; mode 2: fused output head
__global__ __launch_bounds__(256) void node_mfma_kernel(
    __hip_bfloat16* __restrict__ h16,
    const float* __restrict__ agg,
    float* __restrict__ posb, const float* __restrict__ pdel,
    const __hip_bfloat16* __restrict__ W1p, const float* __restrict__ b1,
    const __hip_bfloat16* __restrict__ W2p, const float* __restrict__ b2,
    const __hip_bfloat16* __restrict__ nxtW1p, const float* __restrict__ nxt_b1,
    const __hip_bfloat16* __restrict__ nxt_cW1p, const float* __restrict__ nxt_cb1,
    const float* __restrict__ nxt_cW2, const float* __restrict__ nxt_cb2,
    __hip_bfloat16* __restrict__ U16, __hip_bfloat16* __restrict__ V16,
    float* __restrict__ wnum,
    const __hip_bfloat16* __restrict__ oW1p, const float* __restrict__ ob1,
    const __hip_bfloat16* __restrict__ oW2p, const float* __restrict__ ob2,
    float* __restrict__ outp,
    int N, int mode)
{
    __shared__ __hip_bfloat16 a_t[64][264];   // [h | agg] then [newh | agg]
    __shared__ __hip_bfloat16 us[64][136];
    __shared__ float redw[64][4];
    const int t = threadIdx.x;
    const int nb = blockIdx.x * 64;
    const int lane = t & 63, w = t >> 6, g = lane >> 4, l15 = lane & 15;

    #pragma unroll
    for (int it = 0; it < 4; ++it) {
        int flat = t + 256 * it;
        int c = flat & 15, e = flat >> 4;
        int node = nb + e; if (node >= N) node = N - 1;
        *(int4*)(&a_t[e][c * 8]) = *(const int4*)(h16 + (size_t)node * 128 + c * 8);
    }
    #pragma unroll
    for (int it = 0; it < 8; ++it) {
        int flat = t + 256 * it;
        int c = flat & 31, e = flat >> 5;
        int node = nb + e; if (node >= N) node = N - 1;
        float4 v = *(const float4*)(agg + (size_t)node * 128 + c * 4);
        __hip_bfloat16* p = &a_t[e][128 + c * 4];
        p[0] = __float2bfloat16(v.x); p[1] = __float2bfloat16(v.y);
        p[2] = __float2bfloat16(v.z); p[3] = __float2bfloat16(v.w);
    }
    __syncthreads();

    const int colA = w * 32 + l15, colB = colA + 16;
    f32x4 acc[4][2];

    zacc(acc);
    mfma_gemm<264>(a_t, 0, W1p, 8, w, lane, acc);
    {
        float b1a = b1[colA], b1b = b1[colB];
        #pragma unroll
        for (int r = 0; r < 4; ++r)
            #pragma unroll
            for (int q = 0; q < 4; ++q) {
                int row = r * 16 + g * 4 + q;
                us[row][colA] = __float2bfloat16(silu_f(acc[r][0][q] + b1a));
                us[row][colB] = __float2bfloat16(silu_f(acc[r][1][q] + b1b));
            }
    }
    __syncthreads();

    zacc(acc);
    mfma_gemm<136>(us, 0, W2p, 4, w, lane, acc);
    {
        float b2a = b2[colA], b2b = b2[colB];
        #pragma unroll
        for (int r = 0; r < 4; ++r)
            #pragma unroll
            for (int q = 0; q < 4; ++q) {
                int row = r * 16 + g * 4 + q;
                int node = nb + row;
                if (node < N) {
                    size_t off = (size_t)node * 128;
                    float va = bf2f(*(const short*)&a_t[row][colA]) + acc[r][0][q] + b2a;
                    float vb = bf2f(*(const short*)&a_t[row][colB]) + acc[r][1][q] + b2b;
                    __hip_bfloat16 ha = __float2bfloat16(va), hb = __float2bfloat16(vb);
                    h16[off + colA] = ha; h16[off + colB] = hb;
                    a_t[row][colA] = ha; a_t[row][colB] = hb;
                } else {
                    a_t[row][colA] = __float2bfloat16(0.f);
                    a_t[row][colB] = __float2bfloat16(0.f);
                }
            }
    }
    if (t < 192) {
        int e = t / 3, comp = t % 3;
        int node = nb + e;
        if (node < N) posb[3 * node + comp] += pdel[3 * node + comp];
    }

    if (mode == 0) return;
    __syncthreads();   // newh staged in a_t[.][0..127]; all us reads done

    if (mode == 2) {
        // fused output head: out = silu(newh@oW1+ob1)@oW2 + ob2
        zacc(acc);
        mfma_gemm<264>(a_t, 0, oW1p, 4, w, lane, acc);
        {
            float b1a = ob1[colA], b1b = ob1[colB];
            #pragma unroll
            for (int r = 0; r < 4; ++r)
                #pragma unroll
                for (int q = 0; q < 4; ++q) {
                    int row = r * 16 + g * 4 + q;
                    us[row][colA] = __float2bfloat16(silu_f(acc[r][0][q] + b1a));
                    us[row][colB] = __float2bfloat16(silu_f(acc[r][1][q] + b1b));
                }
        }
        __syncthreads();
        zacc(acc);
        mfma_gemm<136>(us, 0, oW2p, 4, w, lane, acc);
        {
            float b2a = ob2[colA], b2b = ob2[colB];
            #pragma unroll
            for (int r = 0; r < 4; ++r)
                #pragma unroll
                for (int q = 0; q < 4; ++q) {
                    int row = r * 16 + g * 4 + q;
                    int node = nb + row;
                    if (node < N) {
                        outp[(size_t)node * 128 + colA] = acc[r][0][q] + b2a;
                        outp[(size_t)node * 128 + colB] = acc[r][1][q] + b2b;
                    }
                }
        }
        return;
    }

    // mode 1: precompute for next layer
    zacc(acc);
    mfma_gemm<264>(a_t, 0, nxtW1p, 4, w, lane, acc);
    {
        float bA = nxt_b1[colA], bB = nxt_b1[colB];
        #pragma unroll
        for (int r = 0; r < 4; ++r)
            #pragma unroll
            for (int q = 0; q < 4; ++q) {
                int node = nb + r * 16 + g * 4 + q;
                if (node < N) {
                    U16[(size_t)node * 128 + colA] = __float2bfloat16(acc[r][0][q] + bA);
                    U16[(size_t)node * 128 + colB] = __float2bfloat16(acc[r][1][q] + bB);
                }
            }
    }
    zacc(acc);
    mfma_gemm<264>(a_t, 0, nxtW1p + 4 * 4096, 4, w, lane, acc);
    #pragma unroll
    for (int r = 0; r < 4; ++r)
        #pragma unroll
        for (int q = 0; q < 4; ++q) {
            int node = nb + r * 16 + g * 4 + q;
            if (node < N) {
                V16[(size_t)node * 128 + colA] = __float2bfloat16(acc[r][0][q]);
                V16[(size_t)node * 128 + colB] = __float2bfloat16(acc[r][1][q]);
            }
        }
    zacc(acc);
    mfma_gemm<264>(a_t, 0, nxt_cW1p, 4, w, lane, acc);
    {
        float cb1A = nxt_cb1[colA], cb1B = nxt_cb1[colB];
        float wA = nxt_cW2[colA], wB = nxt_cW2[colB];
        #pragma unroll
        for (int r = 0; r < 4; ++r)
            #pragma unroll
            for (int q = 0; q < 4; ++q) {
                float p = silu_f(acc[r][0][q] + cb1A) * wA
                        + silu_f(acc[r][1][q] + cb1B) * wB;
                p += __shfl_xor(p, 1);
                p += __shfl_xor(p, 2);
                p += __shfl_xor(p, 4);
                p += __shfl_xor(p, 8);
                if (l15 == 0) redw[r * 16 + g * 4 + q][w] = p;
            }
    }
    __syncthreads();
    if (t < 64 && nb + t < N)
        wnum[nb + t] = redw[t][0] + redw[t][1] + redw[t][2] + redw[t][3] + nxt_cb2[0];
}

// =======================
extern "C" void kernel_launch(void* const* d_in, const int* in_sizes, int n_in,
                              void* d_out, int out_size, void* d_ws, size_t ws_size,
                              hipStream_t stream)
{
    const float* hin  = (const float*)d_in[0];
    const float* pos  = (const float*)d_in[1];
    const int*   ei   = (const int*)d_in[2];
    const float* embW = (const float*)d_in[3];
    const float* embb = (const float*)d_in[4];
    const float* mW1  = (const float*)d_in[5];
    const float* mb1  = (const float*)d_in[6];
    const float* mW2  = (const float*)d_in[7];
    const float* mb2  = (const float*)d_in[8];
    const float* cW1  = (const float*)d_in[9];
    const float* cb1  = (const float*)d_in[10];
    const float* cW2  = (const float*)d_in[11];
    const float* cb2  = (const float*)d_in[12];
    const float* nW1  = (const float*)d_in[13];
    const float* nb1  = (const float*)d_in[14];
    const float* nW2  = (const float*)d_in[15];
    const float* nb2  = (const float*)d_in[16];
    const float* oW1  = (const float*)d_in[17];
    const float* ob1  = (const float*)d_in[18];
    const float* oW2  = (const float*)d_in[19];
    const float* ob2  = (const float*)d_in[20];

    const int N = in_sizes[0] / 64;
    const int E = in_sizes[2] / 2;
    const int Etot = E + N;

    float* aggb = (float*)d_ws;                                  // N*128 f32
    float* posb = aggb + (size_t)N * 128;                        // N*3
    float* pdel = posb + (size_t)N * 3;                          // N*3
    float* wnum = pdel + (size_t)N * 3;                          // N f32
    __hip_bfloat16* h16 = (__hip_bfloat16*)(wnum + N);           // N*128 bf16
    __hip_bfloat16* U16 = h16 + (size_t)N * 128;                 // N*128 bf16
    __hip_bfloat16* V16 = U16 + (size_t)N * 128;                 // N*128 bf16
    __hip_bfloat16* packed = V16 + (size_t)N * 128;              // 122*4096 bf16
    int* cnt  = (int*)(packed + 122 * 4096);                     // N
    int* soff = cnt + N;                                         // N
    int* part = soff + N;                                        // 64
    int* esrc = part + 64;                                       // Etot
    int* edst = esrc + Etot;                                     // Etot
    float* outp = (float*)d_out;

    PackArgs pa;
    int nm = 0; unsigned int poff = 0; int totalChunks = 0;
    auto addm = [&](const float* s, int kc) {
        pa.src[nm] = s; pa.doff[nm] = poff; pa.nchunk[nm] = kc;
        poff += (unsigned int)kc * 4096; totalChunks += kc; ++nm;
    };
    for (int l = 0; l < 4; ++l) {
        addm(mW1 + (size_t)l * 257 * 128, 8);
        addm(mW2 + (size_t)l * 128 * 128, 4);
        addm(cW1 + (size_t)l * 128 * 128, 4);
        addm(nW1 + (size_t)l * 256 * 128, 8);
        addm(nW2 + (size_t)l * 128 * 128, 4);
    }
    addm(oW1, 4);
    addm(oW2, 4);
    addm(embW, 2);
    pa.nmat = nm;

    const unsigned int LSTRIDE = 28 * 4096;
    const __hip_bfloat16* oW1p  = packed + (size_t)4 * LSTRIDE;
    const __hip_bfloat16* oW2p  = packed + (size_t)4 * LSTRIDE + 4 * 4096;
    const __hip_bfloat16* embWp = packed + (size_t)4 * LSTRIDE + 8 * 4096;

    hipMemcpyAsync(posb, pos, (size_t)N * 3 * sizeof(float),
                   hipMemcpyDeviceToDevice, stream);
    repack_kernel<<<totalChunks, 256, 0, stream>>>(pa, packed);

    const int scanBlocks = (N + 4095) / 4096;
    hipMemsetAsync(cnt, 0, (size_t)N * sizeof(int), stream);
    hist_kernel<<<(Etot + 255) / 256, 256, 0, stream>>>(ei, cnt, E, N);
    scan_block_kernel<<<scanBlocks, 256, 0, stream>>>(cnt, soff, part, N);
    scan_part_kernel<<<1, 64, 0, stream>>>(part, scanBlocks);
    scan_add_kernel<<<scanBlocks, 256, 0, stream>>>(soff, part, N);
    scatter_kernel<<<(Etot + 255) / 256, 256, 0, stream>>>(ei, soff, esrc, edst, E, N);

    const int nodeBlocks64 = (N + 63) / 64;
    const int edgeBlocks   = (Etot + 63) / 64;

    embed_pre_kernel<<<nodeBlocks64, 256, 0, stream>>>(
        hin, embWp, embb,
        packed, mb1, packed + 12 * 4096,
        cb1, cW2, cb2,
        h16, U16, V16, wnum, N);

    for (int l = 0; l < 4; ++l) {
        hipMemsetAsync(aggb, 0, (size_t)N * 128 * sizeof(float), stream);
        hipMemsetAsync(pdel, 0, (size_t)N * 3 * sizeof(float), stream);
        const __hip_bfloat16* lp = packed + (size_t)l * LSTRIDE;
        edge_kernel<<<edgeBlocks, 256, 0, stream>>>(
            U16, V16, wnum, posb, esrc, edst,
            mW1 + (size_t)l * 257 * 128 + 256 * 128,
            lp + 8 * 4096, mb2 + l * 128,
            aggb, pdel, Etot);
        const int ln = (l < 3) ? (l + 1) : l;
        const __hip_bfloat16* lpn = packed + (size_t)ln * LSTRIDE;
        node_mfma_kernel<<<nodeBlocks64, 256, 0, stream>>>(
            h16, aggb, posb, pdel,
            lp + 16 * 4096, nb1 + l * 128,
            lp + 24 * 4096, nb2 + l * 128,
            lpn, mb1 + (size_t)ln * 128,
            lpn + 12 * 4096, cb1 + (size_t)ln * 128,
            cW2 + (size_t)ln * 128, cb2 + ln,
            U16, V16, wnum,
            oW1p, ob1, oW2p, ob2, outp,
            N, (l < 3) ? 1 : 2);
    }

    hipMemcpyAsync(outp + (size_t)N * 128, posb, (size_t)N * 3 * sizeof(float),
                   hipMemcpyDeviceToDevice, stream);
}